// Round 5
// baseline (53.032 us; speedup 1.0000x reference)
//
#include <hip/hip_runtime.h>
#include <hip/hip_bf16.h>

#define HIDDEN 64
#define BATCH 2048
#define SFULL 1024
#define SM1 1023
#define LN_CLAMP -23.025850929940457f  // ln(1e-10)
#define PAIRS 8                        // 16 sp per block (grid.y = 64)

typedef __bf16 bf16x8 __attribute__((ext_vector_type(8)));
typedef float  f32x4  __attribute__((ext_vector_type(4)));

// Row permutation mapping MFMA D-layout rows to MFMA B-layout k-indices.
// For rho = 16*mt + 4*gg + r:  perm(rho) = 32*(mt>>1) + 8*gg + 4*(mt&1) + r.
// Hardware-verified in R2/R3 (absmax 0.0).
__device__ __forceinline__ int permrow(int rho) {
    return 32 * ((rho >> 4) >> 1) + 8 * ((rho >> 2) & 3) + 4 * ((rho >> 4) & 1) + (rho & 3);
}

// ---------------- Kernel 1: 3-layer MLP fully on MFMA, 2 sp-chains/iter ----
// grid (32, 64), block 256 (4 waves). Wave w: 16 points b = (bx*4+w)*16+col.
// 2048 blocks -> 8 blocks/CU queued; VGPR(68) allows ~7 waves/SIMD resident.
// Each loop iteration runs TWO independent chains (sp, sp+1) sharing loads:
//   MFMA1 x4 : h1pre^perm = permW1^T @ [xt,t,x0,1]^T (bias folded into k=3)
//   relu+cvt -> B-frag (in-lane)  -> MFMA2 x8 -> relu+cvt -> MFMA3 x2
// Lanes g=0 hold c0,c1,c2; Hermite + store. No shuffles, no LDS.
__global__ __launch_bounds__(256, 3) void mlp_z_kernel(
    const float* __restrict__ ys,    // (B, S, 2)
    const float* __restrict__ W1,    // (3, 64)
    const float* __restrict__ b1,    // (64)
    const float* __restrict__ W2,    // (64, 64) row-major [k][h]
    const float* __restrict__ b2,    // (64)
    const float* __restrict__ Wout,  // (64, 3)
    const float* __restrict__ bout,  // (3)
    float* __restrict__ z)           // (SM1, BATCH)
{
    const int lane = threadIdx.x & 63;
    const int wv   = threadIdx.x >> 6;
    const int col  = lane & 15;      // point index within tile
    const int g    = lane >> 4;      // k-group

    const int b   = (blockIdx.x * 4 + wv) * 16 + col;
    const int sp0 = blockIdx.y * (2 * PAIRS);
    const int omax = (SFULL - 1) - sp0;  // last valid float2 offset from base2

    // ---- loop-invariant per-lane weight fragments ----
    // MFMA1 A: k<3 -> W1[k][perm], k==3 -> b1[perm] (bias row), else 0
    bf16x8 a1[4];
    // MFMA2 A: A2[16mt+col][32c+8g+j] = W2[32c+8g+j][perm(16mt+col)]
    bf16x8 a2[4][2];
    // MFMA3 A: A3[col][32c+8g+j] = (col<3) ? Wout[32c+8g+j][col] : 0
    bf16x8 a3[2];
#pragma unroll
    for (int mt = 0; mt < 4; ++mt) {
        const int p2 = permrow(16 * mt + col);
#pragma unroll
        for (int j = 0; j < 8; ++j) {
            const int k = 8 * g + j;
            a1[mt][j] = (k < 3) ? (__bf16)W1[k * 64 + p2]
                      : (k == 3) ? (__bf16)b1[p2] : (__bf16)0.0f;
        }
#pragma unroll
        for (int c = 0; c < 2; ++c)
#pragma unroll
            for (int j = 0; j < 8; ++j)
                a2[mt][c][j] = (__bf16)W2[(32 * c + 8 * g + j) * 64 + p2];
    }
#pragma unroll
    for (int c = 0; c < 2; ++c)
#pragma unroll
        for (int j = 0; j < 8; ++j)
            a3[c][j] = (col < 3) ? (__bf16)Wout[(32 * c + 8 * g + j) * 3 + col] : (__bf16)0.0f;

    // layer-2 bias C-init (D-layout rows: perm(16mt + 4g + r))
    f32x4 c2init[4];
#pragma unroll
    for (int mt = 0; mt < 4; ++mt)
#pragma unroll
        for (int r = 0; r < 4; ++r)
            c2init[mt][r] = b2[permrow(16 * mt + 4 * g + r)];
    f32x4 c3init = {0.f, 0.f, 0.f, 0.f};
    if (g == 0) { c3init[0] = bout[0]; c3init[1] = bout[1]; c3init[2] = bout[2]; }

    const f32x4 zero4 = {0.f, 0.f, 0.f, 0.f};

    const float2* base2 = reinterpret_cast<const float2*>(ys) + ((size_t)b * SFULL + sp0);
    float* zb = z + (size_t)sp0 * BATCH + b;

    float2 qa = base2[0];
    float2 qb = base2[1];
    float2 qc = base2[2];

    for (int it = 0; it < PAIRS; ++it) {
        // prefetch next pair's inputs (offsets clamped -> always in-bounds)
        const int o1n = min(2 * it + 3, omax);
        const int o2n = min(2 * it + 4, omax);
        const float2 nb = base2[o1n];
        const float2 nc = base2[o2n];

        // chain A: sp = sp0+2it ; chain B: sp+1
        const float x0a = qa.y, ta = qb.x, xta = qb.y;
        const float x0b = qb.y, tb = qc.x, xtb = qc.y;

        // branchless B0 frag: A1 cols k>=4 are zero, so every lane can carry
        // the same pattern; only g==0 lanes' k=0..3 values matter.
        bf16x8 f0a, f0b;
        f0a[0] = (__bf16)xta; f0a[1] = (__bf16)ta;
        f0a[2] = (__bf16)x0a; f0a[3] = (__bf16)1.0f;
        f0a[4] = f0a[0]; f0a[5] = f0a[1]; f0a[6] = f0a[2]; f0a[7] = f0a[3];
        f0b[0] = (__bf16)xtb; f0b[1] = (__bf16)tb;
        f0b[2] = (__bf16)x0b; f0b[3] = (__bf16)1.0f;
        f0b[4] = f0b[0]; f0b[5] = f0b[1]; f0b[6] = f0b[2]; f0b[7] = f0b[3];

        // ---- layer 1 (bias folded in) ----
        f32x4 acc1a[4], acc1b[4];
#pragma unroll
        for (int mt = 0; mt < 4; ++mt) {
            acc1a[mt] = __builtin_amdgcn_mfma_f32_16x16x32_bf16(a1[mt], f0a, zero4, 0, 0, 0);
            acc1b[mt] = __builtin_amdgcn_mfma_f32_16x16x32_bf16(a1[mt], f0b, zero4, 0, 0, 0);
        }

        // relu + cvt -> B-frags (in-lane index shuffle only)
        bf16x8 hfa[2], hfb[2];
#pragma unroll
        for (int c = 0; c < 2; ++c)
#pragma unroll
            for (int j = 0; j < 8; ++j) {
                hfa[c][j] = (__bf16)fmaxf(acc1a[2 * c + (j >> 2)][j & 3], 0.0f);
                hfb[c][j] = (__bf16)fmaxf(acc1b[2 * c + (j >> 2)][j & 3], 0.0f);
            }

        // ---- layer 2 ----
        f32x4 acc2a[4], acc2b[4];
#pragma unroll
        for (int mt = 0; mt < 4; ++mt) {
            acc2a[mt] = __builtin_amdgcn_mfma_f32_16x16x32_bf16(a2[mt][0], hfa[0], c2init[mt], 0, 0, 0);
            acc2b[mt] = __builtin_amdgcn_mfma_f32_16x16x32_bf16(a2[mt][0], hfb[0], c2init[mt], 0, 0, 0);
        }
#pragma unroll
        for (int mt = 0; mt < 4; ++mt) {
            acc2a[mt] = __builtin_amdgcn_mfma_f32_16x16x32_bf16(a2[mt][1], hfa[1], acc2a[mt], 0, 0, 0);
            acc2b[mt] = __builtin_amdgcn_mfma_f32_16x16x32_bf16(a2[mt][1], hfb[1], acc2b[mt], 0, 0, 0);
        }

        bf16x8 h2fa[2], h2fb[2];
#pragma unroll
        for (int c = 0; c < 2; ++c)
#pragma unroll
            for (int j = 0; j < 8; ++j) {
                h2fa[c][j] = (__bf16)fmaxf(acc2a[2 * c + (j >> 2)][j & 3], 0.0f);
                h2fb[c][j] = (__bf16)fmaxf(acc2b[2 * c + (j >> 2)][j & 3], 0.0f);
            }

        // ---- layer 3 ----
        f32x4 acc3a, acc3b;
        acc3a = __builtin_amdgcn_mfma_f32_16x16x32_bf16(a3[0], h2fa[0], c3init, 0, 0, 0);
        acc3b = __builtin_amdgcn_mfma_f32_16x16x32_bf16(a3[0], h2fb[0], c3init, 0, 0, 0);
        acc3a = __builtin_amdgcn_mfma_f32_16x16x32_bf16(a3[1], h2fa[1], acc3a, 0, 0, 0);
        acc3b = __builtin_amdgcn_mfma_f32_16x16x32_bf16(a3[1], h2fb[1], acc3b, 0, 0, 0);

        // Hermite: z = c0 + c1*(2x) + c2*(4x^2-2)
        const float zva = fmaf(acc3a[2], fmaf(4.0f * xta, xta, -2.0f),
                          fmaf(acc3a[1], xta + xta, acc3a[0]));
        const float zvb = fmaf(acc3b[2], fmaf(4.0f * xtb, xtb, -2.0f),
                          fmaf(acc3b[1], xtb + xtb, acc3b[0]));

        if (lane < 16) {
            zb[(size_t)(2 * it) * BATCH] = zva;
            if (sp0 + 2 * it + 1 < SM1)  // only skips (by=63, it=7) second sp
                zb[(size_t)(2 * it + 1) * BATCH] = zvb;
        }

        qa = qc; qb = nb; qc = nc;
    }
}

// ---------------- reduction helpers ----------------
__device__ __forceinline__ float blk_reduce_max(float v) {
    __shared__ float s[4];
#pragma unroll
    for (int off = 32; off >= 1; off >>= 1) v = fmaxf(v, __shfl_xor(v, off));
    if ((threadIdx.x & 63) == 0) s[threadIdx.x >> 6] = v;
    __syncthreads();
    v = fmaxf(fmaxf(s[0], s[1]), fmaxf(s[2], s[3]));
    __syncthreads();
    return v;
}

__device__ __forceinline__ float blk_reduce_sum(float v) {
    __shared__ float s[4];
#pragma unroll
    for (int off = 32; off >= 1; off >>= 1) v += __shfl_xor(v, off);
    if ((threadIdx.x & 63) == 0) s[threadIdx.x >> 6] = v;
    __syncthreads();
    v = (s[0] + s[1]) + (s[2] + s[3]);
    __syncthreads();
    return v;
}

// ---------------- Kernel 2: per-column softmax + logclip sum ----------------
__global__ __launch_bounds__(256) void col_softmax_kernel(
    const float* __restrict__ z, float* __restrict__ colsum)
{
    const int sp = blockIdx.x;
    const int tid = threadIdx.x;
    const float* col = z + (size_t)sp * BATCH;

    float vals[8];
    float m = -3.4e38f;
#pragma unroll
    for (int i = 0; i < 8; ++i) {
        vals[i] = col[tid + 256 * i];
        m = fmaxf(m, vals[i]);
    }
    const float M = blk_reduce_max(m);

    float se = 0.0f;
#pragma unroll
    for (int i = 0; i < 8; ++i) se += __expf(vals[i] - M);
    const float S = blk_reduce_sum(se);
    const float L = __logf(S);

    float acc = 0.0f;
#pragma unroll
    for (int i = 0; i < 8; ++i) acc += fmaxf(vals[i] - M - L, LN_CLAMP);
    const float T = blk_reduce_sum(acc);
    if (tid == 0) colsum[sp] = T;
}

// ---------------- Kernel 3: final scalar ----------------
__global__ __launch_bounds__(256) void final_reduce_kernel(
    const float* __restrict__ colsum, float* __restrict__ out)
{
    const int tid = threadIdx.x;
    float v = 0.0f;
    for (int i = tid; i < SM1; i += 256) v += colsum[i];
    const float T = blk_reduce_sum(v);
    if (tid == 0) out[0] = T / (float)BATCH;
}

extern "C" void kernel_launch(void* const* d_in, const int* in_sizes, int n_in,
                              void* d_out, int out_size, void* d_ws, size_t ws_size,
                              hipStream_t stream) {
    const float* ys   = (const float*)d_in[0];
    const float* W1   = (const float*)d_in[1];
    const float* b1   = (const float*)d_in[2];
    const float* W2   = (const float*)d_in[3];
    const float* b2   = (const float*)d_in[4];
    const float* Wout = (const float*)d_in[5];
    const float* bout = (const float*)d_in[6];
    float* out = (float*)d_out;

    float* z      = (float*)d_ws;                       // SM1*BATCH floats
    float* colsum = z + (size_t)SM1 * BATCH;            // SM1 floats

    dim3 grid1(32, 64);  // 32*4 waves * 16 pts = 2048 b ; 64*16 = 1024 sp slots
    mlp_z_kernel<<<grid1, 256, 0, stream>>>(ys, W1, b1, W2, b2, Wout, bout, z);
    col_softmax_kernel<<<SM1, 256, 0, stream>>>(z, colsum);
    final_reduce_kernel<<<1, 256, 0, stream>>>(colsum, out);
}

// Round 6
// 49.907 us; speedup vs baseline: 1.0626x; 1.0626x over previous
//
#include <hip/hip_runtime.h>
#include <hip/hip_bf16.h>

#define HIDDEN 64
#define BATCH 2048
#define SFULL 1024
#define SM1 1023
#define LN_CLAMP -23.025850929940457f  // ln(1e-10)
#define PAIRS 8                        // 16 sp per block (grid.y = 64)

typedef __bf16 bf16x8 __attribute__((ext_vector_type(8)));
typedef float  f32x4  __attribute__((ext_vector_type(4)));

// Fragment cache layout in workspace: 19 units of [64 lanes][16B].
//  u 0..3  : a1[mt]      (bf16x8)
//  u 4..11 : a2[mt][c]   (u = 4 + mt*2 + c)
//  u 12,13 : a3[c]
//  u 14..17: c2init[mt]  (f32x4)
//  u 18    : c3init      (f32x4)
#define FRAG_UNITS 19
#define FRAG_BYTES (FRAG_UNITS * 64 * 16)

// Row permutation mapping MFMA D-layout rows to MFMA B-layout k-indices.
// For rho = 16*mt + 4*gg + r:  perm(rho) = 32*(mt>>1) + 8*gg + 4*(mt&1) + r.
// Hardware-verified in R2-R4 (absmax 0.0).
__device__ __forceinline__ int permrow(int rho) {
    return 32 * ((rho >> 4) >> 1) + 8 * ((rho >> 2) & 3) + 4 * ((rho >> 4) & 1) + (rho & 3);
}

// ---------------- Kernel 0: one-time fragment gather (1 block) -------------
// The per-lane MFMA weight fragments are identical for every wave in the main
// grid; gather the scattered weights ONCE here, store [unit][lane] coalesced.
// Work split across the 4 waves to parallelize the scattered-load latency.
__global__ __launch_bounds__(256) void frag_setup_kernel(
    const float* __restrict__ W1, const float* __restrict__ b1,
    const float* __restrict__ W2, const float* __restrict__ b2,
    const float* __restrict__ Wout, const float* __restrict__ bout,
    char* __restrict__ F)
{
    const int lane = threadIdx.x & 63;
    const int wv   = threadIdx.x >> 6;
    const int col  = lane & 15;
    const int g    = lane >> 4;

    if (wv == 0) {
        // a1 (bias folded into k=3) + a3 + c3init
#pragma unroll
        for (int mt = 0; mt < 4; ++mt) {
            const int p2 = permrow(16 * mt + col);
            bf16x8 v;
#pragma unroll
            for (int j = 0; j < 8; ++j) {
                const int k = 8 * g + j;
                v[j] = (k < 3) ? (__bf16)W1[k * 64 + p2]
                     : (k == 3) ? (__bf16)b1[p2] : (__bf16)0.0f;
            }
            *(bf16x8*)(F + ((mt * 64 + lane) << 4)) = v;
        }
#pragma unroll
        for (int c = 0; c < 2; ++c) {
            bf16x8 v;
#pragma unroll
            for (int j = 0; j < 8; ++j)
                v[j] = (col < 3) ? (__bf16)Wout[(32 * c + 8 * g + j) * 3 + col] : (__bf16)0.0f;
            *(bf16x8*)(F + (((12 + c) * 64 + lane) << 4)) = v;
        }
        f32x4 c3 = {0.f, 0.f, 0.f, 0.f};
        if (g == 0) { c3[0] = bout[0]; c3[1] = bout[1]; c3[2] = bout[2]; }
        *(f32x4*)(F + ((18 * 64 + lane) << 4)) = c3;
    } else if (wv == 1 || wv == 2) {
        // a2 for mt = {0,1} (wv 1) or {2,3} (wv 2)
#pragma unroll
        for (int m = 0; m < 2; ++m) {
            const int mt = (wv - 1) * 2 + m;
            const int p2 = permrow(16 * mt + col);
#pragma unroll
            for (int c = 0; c < 2; ++c) {
                bf16x8 v;
#pragma unroll
                for (int j = 0; j < 8; ++j)
                    v[j] = (__bf16)W2[(32 * c + 8 * g + j) * 64 + p2];
                *(bf16x8*)(F + (((4 + mt * 2 + c) * 64 + lane) << 4)) = v;
            }
        }
    } else {
        // c2init
#pragma unroll
        for (int mt = 0; mt < 4; ++mt) {
            f32x4 v;
#pragma unroll
            for (int r = 0; r < 4; ++r)
                v[r] = b2[permrow(16 * mt + 4 * g + r)];
            *(f32x4*)(F + (((14 + mt) * 64 + lane) << 4)) = v;
        }
    }
}

// ---------------- Kernel 1: 3-layer MLP fully on MFMA, 2 sp-chains/iter ----
// grid (32, 64), block 256 (4 waves). Wave w: 16 points b = (bx*4+w)*16+col.
// Preamble = 19 coalesced dwordx4 loads from the fragment cache (L2-hot).
// Each loop iteration runs TWO independent chains (sp, sp+1) sharing loads:
//   MFMA1 x4 -> relu+cvt -> MFMA2 x8 -> relu+cvt -> MFMA3 x2 ; Hermite+store.
__global__ __launch_bounds__(256, 3) void mlp_z_kernel(
    const float* __restrict__ ys,    // (B, S, 2)
    const char* __restrict__ F,      // fragment cache
    float* __restrict__ z)           // (SM1, BATCH)
{
    const int lane = threadIdx.x & 63;
    const int wv   = threadIdx.x >> 6;
    const int col  = lane & 15;

    const int b   = (blockIdx.x * 4 + wv) * 16 + col;
    const int sp0 = blockIdx.y * (2 * PAIRS);
    const int omax = (SFULL - 1) - sp0;  // last valid float2 offset from base2

    // ---- coalesced fragment loads ----
    bf16x8 a1[4], a2[4][2], a3[2];
    f32x4 c2init[4], c3init;
#pragma unroll
    for (int mt = 0; mt < 4; ++mt) {
        a1[mt]       = *(const bf16x8*)(F + ((mt * 64 + lane) << 4));
        a2[mt][0]    = *(const bf16x8*)(F + (((4 + mt * 2) * 64 + lane) << 4));
        a2[mt][1]    = *(const bf16x8*)(F + (((5 + mt * 2) * 64 + lane) << 4));
        c2init[mt]   = *(const f32x4*)(F + (((14 + mt) * 64 + lane) << 4));
    }
    a3[0]  = *(const bf16x8*)(F + ((12 * 64 + lane) << 4));
    a3[1]  = *(const bf16x8*)(F + ((13 * 64 + lane) << 4));
    c3init = *(const f32x4*)(F + ((18 * 64 + lane) << 4));

    const f32x4 zero4 = {0.f, 0.f, 0.f, 0.f};

    const float2* base2 = reinterpret_cast<const float2*>(ys) + ((size_t)b * SFULL + sp0);
    float* zb = z + (size_t)sp0 * BATCH + b;

    float2 qa = base2[0];
    float2 qb = base2[1];
    float2 qc = base2[2];

    for (int it = 0; it < PAIRS; ++it) {
        // prefetch next pair's inputs (offsets clamped -> always in-bounds)
        const int o1n = min(2 * it + 3, omax);
        const int o2n = min(2 * it + 4, omax);
        const float2 nb = base2[o1n];
        const float2 nc = base2[o2n];

        // chain A: sp = sp0+2it ; chain B: sp+1
        const float x0a = qa.y, ta = qb.x, xta = qb.y;
        const float x0b = qb.y, tb = qc.x, xtb = qc.y;

        // branchless B0 frag (A1 cols k>=4 are zero)
        bf16x8 f0a, f0b;
        f0a[0] = (__bf16)xta; f0a[1] = (__bf16)ta;
        f0a[2] = (__bf16)x0a; f0a[3] = (__bf16)1.0f;
        f0a[4] = f0a[0]; f0a[5] = f0a[1]; f0a[6] = f0a[2]; f0a[7] = f0a[3];
        f0b[0] = (__bf16)xtb; f0b[1] = (__bf16)tb;
        f0b[2] = (__bf16)x0b; f0b[3] = (__bf16)1.0f;
        f0b[4] = f0b[0]; f0b[5] = f0b[1]; f0b[6] = f0b[2]; f0b[7] = f0b[3];

        // ---- layer 1 (bias folded in) ----
        f32x4 acc1a[4], acc1b[4];
#pragma unroll
        for (int mt = 0; mt < 4; ++mt) {
            acc1a[mt] = __builtin_amdgcn_mfma_f32_16x16x32_bf16(a1[mt], f0a, zero4, 0, 0, 0);
            acc1b[mt] = __builtin_amdgcn_mfma_f32_16x16x32_bf16(a1[mt], f0b, zero4, 0, 0, 0);
        }

        // relu + cvt -> B-frags (in-lane index shuffle only)
        bf16x8 hfa[2], hfb[2];
#pragma unroll
        for (int c = 0; c < 2; ++c)
#pragma unroll
            for (int j = 0; j < 8; ++j) {
                hfa[c][j] = (__bf16)fmaxf(acc1a[2 * c + (j >> 2)][j & 3], 0.0f);
                hfb[c][j] = (__bf16)fmaxf(acc1b[2 * c + (j >> 2)][j & 3], 0.0f);
            }

        // ---- layer 2 ----
        f32x4 acc2a[4], acc2b[4];
#pragma unroll
        for (int mt = 0; mt < 4; ++mt) {
            acc2a[mt] = __builtin_amdgcn_mfma_f32_16x16x32_bf16(a2[mt][0], hfa[0], c2init[mt], 0, 0, 0);
            acc2b[mt] = __builtin_amdgcn_mfma_f32_16x16x32_bf16(a2[mt][0], hfb[0], c2init[mt], 0, 0, 0);
        }
#pragma unroll
        for (int mt = 0; mt < 4; ++mt) {
            acc2a[mt] = __builtin_amdgcn_mfma_f32_16x16x32_bf16(a2[mt][1], hfa[1], acc2a[mt], 0, 0, 0);
            acc2b[mt] = __builtin_amdgcn_mfma_f32_16x16x32_bf16(a2[mt][1], hfb[1], acc2b[mt], 0, 0, 0);
        }

        bf16x8 h2fa[2], h2fb[2];
#pragma unroll
        for (int c = 0; c < 2; ++c)
#pragma unroll
            for (int j = 0; j < 8; ++j) {
                h2fa[c][j] = (__bf16)fmaxf(acc2a[2 * c + (j >> 2)][j & 3], 0.0f);
                h2fb[c][j] = (__bf16)fmaxf(acc2b[2 * c + (j >> 2)][j & 3], 0.0f);
            }

        // ---- layer 3 ----
        f32x4 acc3a, acc3b;
        acc3a = __builtin_amdgcn_mfma_f32_16x16x32_bf16(a3[0], h2fa[0], c3init, 0, 0, 0);
        acc3b = __builtin_amdgcn_mfma_f32_16x16x32_bf16(a3[0], h2fb[0], c3init, 0, 0, 0);
        acc3a = __builtin_amdgcn_mfma_f32_16x16x32_bf16(a3[1], h2fa[1], acc3a, 0, 0, 0);
        acc3b = __builtin_amdgcn_mfma_f32_16x16x32_bf16(a3[1], h2fb[1], acc3b, 0, 0, 0);

        // Hermite: z = c0 + c1*(2x) + c2*(4x^2-2)
        const float zva = fmaf(acc3a[2], fmaf(4.0f * xta, xta, -2.0f),
                          fmaf(acc3a[1], xta + xta, acc3a[0]));
        const float zvb = fmaf(acc3b[2], fmaf(4.0f * xtb, xtb, -2.0f),
                          fmaf(acc3b[1], xtb + xtb, acc3b[0]));

        if (lane < 16) {
            zb[(size_t)(2 * it) * BATCH] = zva;
            if (sp0 + 2 * it + 1 < SM1)  // only skips (by=63, it=7) second sp
                zb[(size_t)(2 * it + 1) * BATCH] = zvb;
        }

        qa = qc; qb = nb; qc = nc;
    }
}

// ---------------- reduction helpers ----------------
__device__ __forceinline__ float blk_reduce_max(float v) {
    __shared__ float s[4];
#pragma unroll
    for (int off = 32; off >= 1; off >>= 1) v = fmaxf(v, __shfl_xor(v, off));
    if ((threadIdx.x & 63) == 0) s[threadIdx.x >> 6] = v;
    __syncthreads();
    v = fmaxf(fmaxf(s[0], s[1]), fmaxf(s[2], s[3]));
    __syncthreads();
    return v;
}

__device__ __forceinline__ float blk_reduce_sum(float v) {
    __shared__ float s[4];
#pragma unroll
    for (int off = 32; off >= 1; off >>= 1) v += __shfl_xor(v, off);
    if ((threadIdx.x & 63) == 0) s[threadIdx.x >> 6] = v;
    __syncthreads();
    v = (s[0] + s[1]) + (s[2] + s[3]);
    __syncthreads();
    return v;
}

// ---------------- Kernel 2: per-column softmax + logclip sum ----------------
__global__ __launch_bounds__(256) void col_softmax_kernel(
    const float* __restrict__ z, float* __restrict__ colsum)
{
    const int sp = blockIdx.x;
    const int tid = threadIdx.x;
    const float* col = z + (size_t)sp * BATCH;

    float vals[8];
    float m = -3.4e38f;
#pragma unroll
    for (int i = 0; i < 8; ++i) {
        vals[i] = col[tid + 256 * i];
        m = fmaxf(m, vals[i]);
    }
    const float M = blk_reduce_max(m);

    float se = 0.0f;
#pragma unroll
    for (int i = 0; i < 8; ++i) se += __expf(vals[i] - M);
    const float S = blk_reduce_sum(se);
    const float L = __logf(S);

    float acc = 0.0f;
#pragma unroll
    for (int i = 0; i < 8; ++i) acc += fmaxf(vals[i] - M - L, LN_CLAMP);
    const float T = blk_reduce_sum(acc);
    if (tid == 0) colsum[sp] = T;
}

// ---------------- Kernel 3: final scalar ----------------
__global__ __launch_bounds__(256) void final_reduce_kernel(
    const float* __restrict__ colsum, float* __restrict__ out)
{
    const int tid = threadIdx.x;
    float v = 0.0f;
    for (int i = tid; i < SM1; i += 256) v += colsum[i];
    const float T = blk_reduce_sum(v);
    if (tid == 0) out[0] = T / (float)BATCH;
}

extern "C" void kernel_launch(void* const* d_in, const int* in_sizes, int n_in,
                              void* d_out, int out_size, void* d_ws, size_t ws_size,
                              hipStream_t stream) {
    const float* ys   = (const float*)d_in[0];
    const float* W1   = (const float*)d_in[1];
    const float* b1   = (const float*)d_in[2];
    const float* W2   = (const float*)d_in[3];
    const float* b2   = (const float*)d_in[4];
    const float* Wout = (const float*)d_in[5];
    const float* bout = (const float*)d_in[6];
    float* out = (float*)d_out;

    float* z      = (float*)d_ws;                         // SM1*BATCH floats
    float* colsum = z + (size_t)SM1 * BATCH;              // SM1 floats
    // fragment cache after colsum, 16B aligned
    size_t fo = ((size_t)SM1 * BATCH + SM1) * sizeof(float);
    fo = (fo + 15) & ~(size_t)15;
    char* F = (char*)d_ws + fo;

    frag_setup_kernel<<<1, 256, 0, stream>>>(W1, b1, W2, b2, Wout, bout, F);
    dim3 grid1(32, 64);  // 32*4 waves * 16 pts = 2048 b ; 64*16 = 1024 sp slots
    mlp_z_kernel<<<grid1, 256, 0, stream>>>(ys, F, z);
    col_softmax_kernel<<<SM1, 256, 0, stream>>>(z, colsum);
    final_reduce_kernel<<<1, 256, 0, stream>>>(colsum, out);
}